// Round 1
// baseline (2599.084 us; speedup 1.0000x reference)
//
#include <hip/hip_runtime.h>
#include <hip/hip_bf16.h>

// AutoregressiveResidualBlock: two gather-GEMMs + BN(relu) epilogues.
// Round 0: correctness-first fp32 tiled SGEMM pair. h1 intermediate stored
// as bf16 (error ~0.02 vs threshold 0.236).
//
// Shapes: bs=16384, din=512, mid=1024, out=512, K=2, D1=2, D2=4.
// l1[b,2c+0]=q1[0][b,c], l1[b,2c+1]=x[b,c]          (in_ch=1024)
// c1[b,m]=sum_j l1[b,j]*w1[m,j]+b1[m]; h1=bn1(relu(c1))
// l2[b,2m+0]=q2[0][b,m], l2[b,2m+1]=h1[b,m]          (2048)
// c2[b,o]=sum_j l2[b,j]*w2[o,j]+b2[o] + sum_j l1[b,j]*wsk[o,j]+bsk[o]
// out=bn2(relu(c2))

#define BM 128
#define BN 128
#define BK 32
#define TM 8
#define TN 8
#define PAD 4
#define BN_EPS 1e-5f

#define BS 16384
#define DIN 512
#define MID 1024
#define OUT 512

__global__ __launch_bounds__(256) void gemm1_kernel(
    const float* __restrict__ x, const float* __restrict__ q1,
    const float* __restrict__ w1, const float* __restrict__ b1,
    const float* __restrict__ s1, const float* __restrict__ bb1,
    const float* __restrict__ m1, const float* __restrict__ v1,
    __hip_bfloat16* __restrict__ h1)
{
    __shared__ float As[BK][BM + PAD];
    __shared__ float Bs[BK][BN + PAD];

    const int n0 = blockIdx.x * BN;   // mid dim
    const int m0 = blockIdx.y * BM;   // batch rows
    const int t  = threadIdx.x;
    const int tn = t & 15, tm = t >> 4;

    float acc[TM][TN];
    #pragma unroll
    for (int i = 0; i < TM; ++i)
        #pragma unroll
        for (int j = 0; j < TN; ++j) acc[i][j] = 0.f;

    for (int k0 = 0; k0 < 2 * DIN; k0 += BK) {
        // A tile: BM x BK gathered from q1[0] (even k) / x (odd k)
        #pragma unroll
        for (int r = 0; r < 16; ++r) {
            int idx = r * 256 + t;
            int m = idx >> 5;
            int k = idx & 31;
            int kk = k0 + k;
            int c = kk >> 1;
            int b = m0 + m;
            float val = (kk & 1) ? x[b * DIN + c] : q1[b * DIN + c];
            As[k][m] = val;
        }
        // B tile: BN x BK from w1 (row-major [mid][in_ch])
        #pragma unroll
        for (int r = 0; r < 16; ++r) {
            int idx = r * 256 + t;
            int n = idx >> 5;
            int k = idx & 31;
            Bs[k][n] = w1[(n0 + n) * (2 * DIN) + k0 + k];
        }
        __syncthreads();
        #pragma unroll
        for (int k = 0; k < BK; ++k) {
            float a[TM], bv[TN];
            *reinterpret_cast<float4*>(&a[0]) = *reinterpret_cast<const float4*>(&As[k][tm * TM]);
            *reinterpret_cast<float4*>(&a[4]) = *reinterpret_cast<const float4*>(&As[k][tm * TM + 4]);
            *reinterpret_cast<float4*>(&bv[0]) = *reinterpret_cast<const float4*>(&Bs[k][tn * TN]);
            *reinterpret_cast<float4*>(&bv[4]) = *reinterpret_cast<const float4*>(&Bs[k][tn * TN + 4]);
            #pragma unroll
            for (int i = 0; i < TM; ++i)
                #pragma unroll
                for (int j = 0; j < TN; ++j)
                    acc[i][j] += a[i] * bv[j];
        }
        __syncthreads();
    }

    // epilogue: +b1, relu, bn1, -> bf16
    float scj[TN], mbj[TN], bbj[TN], bij[TN];
    #pragma unroll
    for (int j = 0; j < TN; ++j) {
        int n = n0 + tn * TN + j;
        bij[j] = b1[n];
        scj[j] = s1[n] * rsqrtf(v1[n] + BN_EPS);
        mbj[j] = m1[n];
        bbj[j] = bb1[n];
    }
    #pragma unroll
    for (int i = 0; i < TM; ++i) {
        int b = m0 + tm * TM + i;
        __hip_bfloat16 pack[8] __attribute__((aligned(16)));
        #pragma unroll
        for (int j = 0; j < TN; ++j) {
            float v = acc[i][j] + bij[j];
            v = fmaxf(v, 0.f);
            v = (v - mbj[j]) * scj[j] + bbj[j];
            pack[j] = __float2bfloat16(v);
        }
        *reinterpret_cast<float4*>(&h1[(size_t)b * MID + n0 + tn * TN]) =
            *reinterpret_cast<const float4*>(pack);
    }
}

__global__ __launch_bounds__(256) void gemm2_kernel(
    const float* __restrict__ x, const float* __restrict__ q1,
    const float* __restrict__ q2, const __hip_bfloat16* __restrict__ h1,
    const float* __restrict__ w2, const float* __restrict__ b2,
    const float* __restrict__ wsk, const float* __restrict__ bsk,
    const float* __restrict__ s2, const float* __restrict__ bb2,
    const float* __restrict__ m2, const float* __restrict__ v2,
    float* __restrict__ out)
{
    __shared__ float As[BK][BM + PAD];
    __shared__ float Bs[BK][BN + PAD];

    const int n0 = blockIdx.x * BN;   // out dim
    const int m0 = blockIdx.y * BM;   // batch rows
    const int t  = threadIdx.x;
    const int tn = t & 15, tm = t >> 4;

    float acc[TM][TN];
    #pragma unroll
    for (int i = 0; i < TM; ++i)
        #pragma unroll
        for (int j = 0; j < TN; ++j) acc[i][j] = 0.f;

    // virtual K = 3072: [0,2048) = l2 vs w2; [2048,3072) = l1 vs w_skip
    for (int k0 = 0; k0 < 3072; k0 += BK) {
        if (k0 < 2048) {
            #pragma unroll
            for (int r = 0; r < 16; ++r) {
                int idx = r * 256 + t;
                int m = idx >> 5;
                int k = idx & 31;
                int kv = k0 + k;
                int mm = kv >> 1;
                int b = m0 + m;
                float val = (kv & 1) ? __bfloat162float(h1[(size_t)b * MID + mm])
                                     : q2[(size_t)b * MID + mm];
                As[k][m] = val;
            }
            #pragma unroll
            for (int r = 0; r < 16; ++r) {
                int idx = r * 256 + t;
                int n = idx >> 5;
                int k = idx & 31;
                Bs[k][n] = w2[(n0 + n) * (2 * MID) + k0 + k];
            }
        } else {
            #pragma unroll
            for (int r = 0; r < 16; ++r) {
                int idx = r * 256 + t;
                int m = idx >> 5;
                int k = idx & 31;
                int kv = k0 + k - 2048;
                int c = kv >> 1;
                int b = m0 + m;
                float val = (kv & 1) ? x[b * DIN + c] : q1[b * DIN + c];
                As[k][m] = val;
            }
            #pragma unroll
            for (int r = 0; r < 16; ++r) {
                int idx = r * 256 + t;
                int n = idx >> 5;
                int k = idx & 31;
                Bs[k][n] = wsk[(n0 + n) * (2 * DIN) + k0 + k - 2048];
            }
        }
        __syncthreads();
        #pragma unroll
        for (int k = 0; k < BK; ++k) {
            float a[TM], bv[TN];
            *reinterpret_cast<float4*>(&a[0]) = *reinterpret_cast<const float4*>(&As[k][tm * TM]);
            *reinterpret_cast<float4*>(&a[4]) = *reinterpret_cast<const float4*>(&As[k][tm * TM + 4]);
            *reinterpret_cast<float4*>(&bv[0]) = *reinterpret_cast<const float4*>(&Bs[k][tn * TN]);
            *reinterpret_cast<float4*>(&bv[4]) = *reinterpret_cast<const float4*>(&Bs[k][tn * TN + 4]);
            #pragma unroll
            for (int i = 0; i < TM; ++i)
                #pragma unroll
                for (int j = 0; j < TN; ++j)
                    acc[i][j] += a[i] * bv[j];
        }
        __syncthreads();
    }

    // epilogue: +b2+bsk, relu, bn2, -> fp32 out
    float scj[TN], mbj[TN], bbj[TN], bij[TN];
    #pragma unroll
    for (int j = 0; j < TN; ++j) {
        int n = n0 + tn * TN + j;
        bij[j] = b2[n] + bsk[n];
        scj[j] = s2[n] * rsqrtf(v2[n] + BN_EPS);
        mbj[j] = m2[n];
        bbj[j] = bb2[n];
    }
    #pragma unroll
    for (int i = 0; i < TM; ++i) {
        int b = m0 + tm * TM + i;
        float o[8] __attribute__((aligned(16)));
        #pragma unroll
        for (int j = 0; j < TN; ++j) {
            float v = acc[i][j] + bij[j];
            v = fmaxf(v, 0.f);
            o[j] = (v - mbj[j]) * scj[j] + bbj[j];
        }
        float* op = &out[(size_t)b * OUT + n0 + tn * TN];
        *reinterpret_cast<float4*>(op)     = *reinterpret_cast<const float4*>(&o[0]);
        *reinterpret_cast<float4*>(op + 4) = *reinterpret_cast<const float4*>(&o[4]);
    }
}

extern "C" void kernel_launch(void* const* d_in, const int* in_sizes, int n_in,
                              void* d_out, int out_size, void* d_ws, size_t ws_size,
                              hipStream_t stream) {
    const float* x   = (const float*)d_in[0];
    const float* q1  = (const float*)d_in[1];  // (2,bs,512,1): slot 0 used
    const float* q2  = (const float*)d_in[2];  // (4,bs,1024,1): slot 0 used
    const float* w1  = (const float*)d_in[3];
    const float* b1  = (const float*)d_in[4];
    const float* w2  = (const float*)d_in[5];
    const float* b2  = (const float*)d_in[6];
    const float* wsk = (const float*)d_in[7];
    const float* bsk = (const float*)d_in[8];
    const float* s1  = (const float*)d_in[9];
    const float* bb1 = (const float*)d_in[10];
    const float* m1  = (const float*)d_in[11];
    const float* v1  = (const float*)d_in[12];
    const float* s2  = (const float*)d_in[13];
    const float* bb2 = (const float*)d_in[14];
    const float* m2  = (const float*)d_in[15];
    const float* v2  = (const float*)d_in[16];
    float* out = (float*)d_out;

    // h1 scratch: 16384x1024 bf16 = 32 MB. Prefer d_ws; fall back to the
    // unused conv2_queue slots 1..3 (192 MB, never read by the reference).
    size_t need = (size_t)BS * MID * sizeof(__hip_bfloat16);
    __hip_bfloat16* h1;
    if (ws_size >= need) {
        h1 = (__hip_bfloat16*)d_ws;
    } else {
        h1 = (__hip_bfloat16*)((float*)d_in[2] + (size_t)BS * MID);
    }

    dim3 block(256);
    dim3 g1(MID / BN, BS / BM);   // (8, 128)
    gemm1_kernel<<<g1, block, 0, stream>>>(x, q1, w1, b1, s1, bb1, m1, v1, h1);

    dim3 g2(OUT / BN, BS / BM);   // (4, 128)
    gemm2_kernel<<<g2, block, 0, stream>>>(x, q1, q2, h1, w2, b2, wsk, bsk,
                                           s2, bb2, m2, v2, out);
}

// Round 2
// 555.793 us; speedup vs baseline: 4.6764x; 4.6764x over previous
//
#include <hip/hip_runtime.h>
#include <hip/hip_bf16.h>

// AutoregressiveResidualBlock — Round 1: bf16 MFMA rewrite (m97 recipe).
//
// K-permutation layout (GEMM invariant under shared K-permutation of A,B):
//   A2[b][k] (bf16, stride 3072):
//     k in [   0,1024): q2[0][b,k]          (even l2 slots, deinterleaved)
//     k in [1024,2048): h1[b,k-1024]        (odd l2 slots; written by gemm1)
//     k in [2048,2560): q1[0][b,k-2048]     (even l1 slots)
//     k in [2560,3072): x[b,k-2560]         (odd l1 slots)
//   w1p[m][k] (K=1024): k<512 -> w1[m][2k], else w1[m][2(k-512)+1]
//   w2p[o][k] (K=3072): [w2 even | w2 odd | wsk even | wsk odd]
// gemm1: A = A2[:,2048:], K=1024, B=w1p -> h1 = bn1(relu(.+b1)) into A2[:,1024:2048]
// gemm2: A = A2,          K=3072, B=w2p -> out = bn2(relu(.+b2+bsk))  (skip folded in K)

#define BS   16384
#define DIN  512
#define MID  1024
#define NOUT 512
#define KA2  3072
#define BN_EPS 1e-5f

typedef __attribute__((ext_vector_type(8))) short bf16x8;
typedef __attribute__((ext_vector_type(4))) float floatx4;

#define GLDS(g, l) __builtin_amdgcn_global_load_lds( \
    (const __attribute__((address_space(1))) void*)(g), \
    (__attribute__((address_space(3))) void*)(l), 16, 0, 0)

__device__ __forceinline__ void cvt_store8(const float* __restrict__ src,
                                           __hip_bfloat16* __restrict__ dst) {
    float4 u = *(const float4*)src;
    float4 v = *(const float4*)(src + 4);
    __hip_bfloat16 tmp[8] __attribute__((aligned(16)));
    tmp[0] = __float2bfloat16(u.x); tmp[1] = __float2bfloat16(u.y);
    tmp[2] = __float2bfloat16(u.z); tmp[3] = __float2bfloat16(u.w);
    tmp[4] = __float2bfloat16(v.x); tmp[5] = __float2bfloat16(v.y);
    tmp[6] = __float2bfloat16(v.z); tmp[7] = __float2bfloat16(v.w);
    *(float4*)dst = *(const float4*)tmp;
}

// q2 -> A2[:,0:1024]; 16384*128 threads, 8 elems each
__global__ __launch_bounds__(256) void prep_q2_kernel(
    const float* __restrict__ q2, __hip_bfloat16* __restrict__ A2) {
    int id = blockIdx.x * 256 + threadIdx.x;
    int b = id >> 7;
    int j = (id & 127) << 3;
    cvt_store8(q2 + (size_t)b * MID + j, A2 + (size_t)b * KA2 + j);
}

// q1 -> A2[:,2048:2560], x -> A2[:,2560:3072]; 16384*64 threads
__global__ __launch_bounds__(256) void prep_q1x_kernel(
    const float* __restrict__ q1, const float* __restrict__ x,
    __hip_bfloat16* __restrict__ A2) {
    int id = blockIdx.x * 256 + threadIdx.x;
    int b = id >> 6;
    int j = (id & 63) << 3;
    cvt_store8(q1 + (size_t)b * DIN + j, A2 + (size_t)b * KA2 + 2048 + j);
    cvt_store8(x  + (size_t)b * DIN + j, A2 + (size_t)b * KA2 + 2560 + j);
}

// deinterleave weights: w1p (1024x1024) then w2p (512x3072)
__global__ __launch_bounds__(256) void prep_w_kernel(
    const float* __restrict__ w1, const float* __restrict__ w2,
    const float* __restrict__ wsk,
    __hip_bfloat16* __restrict__ w1p, __hip_bfloat16* __restrict__ w2p) {
    int id = blockIdx.x * 256 + threadIdx.x;
    if (id < 1024 * 1024) {
        int m = id >> 10, k = id & 1023;
        int src = (k < 512) ? (2 * k) : (2 * (k - 512) + 1);
        w1p[id] = __float2bfloat16(w1[m * 1024 + src]);
    } else {
        int id2 = id - 1024 * 1024;
        int o = id2 / 3072, k = id2 - o * 3072;
        float val;
        if (k < 1024)      val = w2[o * 2048 + 2 * k];
        else if (k < 2048) val = w2[o * 2048 + 2 * (k - 1024) + 1];
        else if (k < 2560) val = wsk[o * 1024 + 2 * (k - 2048)];
        else               val = wsk[o * 1024 + 2 * (k - 2560) + 1];
        w2p[id2] = __float2bfloat16(val);
    }
}

// m97-style 128x128 bf16 MFMA GEMM, BK=32, 256 threads = 2x2 waves of 64x64.
// EPI==1: bn1(relu(+bias_a)) -> bf16 hout (stride strideOut)
// EPI==2: bn2(relu(+bias_a+bias_b)) -> fp32 fout (stride strideOut)
template <int EPI>
__global__ __launch_bounds__(256) void mfma_gemm(
    const __hip_bfloat16* __restrict__ A, const __hip_bfloat16* __restrict__ B,
    int K, long strideA,
    const float* __restrict__ bias_a, const float* __restrict__ bias_b,
    const float* __restrict__ bn_s, const float* __restrict__ bn_b,
    const float* __restrict__ bn_m, const float* __restrict__ bn_v,
    __hip_bfloat16* __restrict__ hout, float* __restrict__ fout, int strideOut)
{
    __shared__ short As[128 * 32];
    __shared__ short Bs[128 * 32];

    const int t = threadIdx.x;
    const int lane = t & 63;
    const int wave = t >> 6;
    const int wm = wave >> 1, wn = wave & 1;
    const int m0 = blockIdx.y * 128;
    const int n0 = blockIdx.x * 128;

    floatx4 acc[4][4];
#pragma unroll
    for (int i = 0; i < 4; ++i)
#pragma unroll
        for (int j = 0; j < 4; ++j)
            acc[i][j] = (floatx4){0.f, 0.f, 0.f, 0.f};

    for (int k0 = 0; k0 < K; k0 += 32) {
        // stage A,B tiles (128x32 bf16 each) via direct-to-LDS 16B loads.
        // LDS dest is wave-uniform base + lane*16 — layout must match.
#pragma unroll
        for (int c = 0; c < 2; ++c) {
            int fb = c * 256 + wave * 64;   // wave-uniform
            int f = fb + lane;              // 0..511: row=f>>2, 8-elem chunk=f&3
            GLDS(A + (size_t)(m0 + (f >> 2)) * strideA + k0 + (f & 3) * 8,
                 As + fb * 8);
            GLDS(B + (size_t)(n0 + (f >> 2)) * (size_t)K + k0 + (f & 3) * 8,
                 Bs + fb * 8);
        }
        __syncthreads();

        bf16x8 af[4], bfr[4];
#pragma unroll
        for (int i = 0; i < 4; ++i)
            af[i] = *(const bf16x8*)&As[(wm * 64 + i * 16 + (lane & 15)) * 32 +
                                        (lane >> 4) * 8];
#pragma unroll
        for (int j = 0; j < 4; ++j)
            bfr[j] = *(const bf16x8*)&Bs[(wn * 64 + j * 16 + (lane & 15)) * 32 +
                                         (lane >> 4) * 8];
#pragma unroll
        for (int i = 0; i < 4; ++i)
#pragma unroll
            for (int j = 0; j < 4; ++j)
                acc[i][j] = __builtin_amdgcn_mfma_f32_16x16x32_bf16(
                    af[i], bfr[j], acc[i][j], 0, 0, 0);
        __syncthreads();
    }

    // epilogue: D frag mapping col=lane&15, row=(lane>>4)*4+r
#pragma unroll
    for (int j = 0; j < 4; ++j) {
        int col = n0 + wn * 64 + j * 16 + (lane & 15);
        float bias = bias_a[col];
        if (EPI == 2) bias += bias_b[col];
        float scale = bn_s[col] * rsqrtf(bn_v[col] + BN_EPS);
        float mean = bn_m[col], beta = bn_b[col];
#pragma unroll
        for (int i = 0; i < 4; ++i) {
            int rbase = m0 + wm * 64 + i * 16 + (lane >> 4) * 4;
#pragma unroll
            for (int r = 0; r < 4; ++r) {
                float v = acc[i][j][r] + bias;
                v = fmaxf(v, 0.f);
                v = (v - mean) * scale + beta;
                if (EPI == 1)
                    hout[(size_t)(rbase + r) * strideOut + col] = __float2bfloat16(v);
                else
                    fout[(size_t)(rbase + r) * strideOut + col] = v;
            }
        }
    }
}

extern "C" void kernel_launch(void* const* d_in, const int* in_sizes, int n_in,
                              void* d_out, int out_size, void* d_ws, size_t ws_size,
                              hipStream_t stream) {
    const float* x   = (const float*)d_in[0];
    const float* q1  = (const float*)d_in[1];
    const float* q2  = (const float*)d_in[2];
    const float* w1  = (const float*)d_in[3];
    const float* b1  = (const float*)d_in[4];
    const float* w2  = (const float*)d_in[5];
    const float* b2  = (const float*)d_in[6];
    const float* wsk = (const float*)d_in[7];
    const float* bsk = (const float*)d_in[8];
    const float* s1  = (const float*)d_in[9];
    const float* bb1 = (const float*)d_in[10];
    const float* m1  = (const float*)d_in[11];
    const float* v1  = (const float*)d_in[12];
    const float* s2  = (const float*)d_in[13];
    const float* bb2 = (const float*)d_in[14];
    const float* m2  = (const float*)d_in[15];
    const float* v2  = (const float*)d_in[16];
    float* out = (float*)d_out;

    // scratch: A2 (96MB) + w1p (2MB) + w2p (3MB). Prefer d_ws; else the
    // unused conv2_queue slots 1..3 (192MB, never read by the reference).
    size_t needA2 = (size_t)BS * KA2 * sizeof(__hip_bfloat16);
    size_t needW  = ((size_t)1024 * 1024 + (size_t)512 * 3072) * sizeof(__hip_bfloat16);
    char* base;
    if (ws_size >= needA2 + needW)
        base = (char*)d_ws;
    else
        base = (char*)d_in[2] + (size_t)BS * MID * sizeof(float);
    __hip_bfloat16* A2  = (__hip_bfloat16*)base;
    __hip_bfloat16* w1p = (__hip_bfloat16*)(base + needA2);
    __hip_bfloat16* w2p = w1p + 1024 * 1024;

    prep_q2_kernel<<<dim3(BS * 128 / 256), dim3(256), 0, stream>>>(q2, A2);
    prep_q1x_kernel<<<dim3(BS * 64 / 256), dim3(256), 0, stream>>>(q1, x, A2);
    prep_w_kernel<<<dim3((1024 * 1024 + 512 * 3072) / 256), dim3(256), 0, stream>>>(
        w1, w2, wsk, w1p, w2p);

    // gemm1: M=16384, N=1024, K=1024; h1 -> A2[:,1024:2048]
    mfma_gemm<1><<<dim3(MID / 128, BS / 128), dim3(256), 0, stream>>>(
        A2 + 2048, w1p, 1024, KA2,
        b1, nullptr, s1, bb1, m1, v1,
        A2 + 1024, nullptr, KA2);

    // gemm2: M=16384, N=512, K=3072 (w2 + skip folded); out fp32
    mfma_gemm<2><<<dim3(NOUT / 128, BS / 128), dim3(256), 0, stream>>>(
        A2, w2p, 3072, KA2,
        b2, bsk, s2, bb2, m2, v2,
        nullptr, out, NOUT);
}

// Round 3
// 547.408 us; speedup vs baseline: 4.7480x; 1.0153x over previous
//
#include <hip/hip_runtime.h>
#include <hip/hip_bf16.h>

// AutoregressiveResidualBlock — Round 2: fused prep (1 kernel), XCD-aware
// block swizzle on both GEMMs, kept m97-style 16x16x32 bf16 MFMA core.
//
// Layout (K-permutation; GEMM invariant under shared K-perm of A and B):
//   A2[b][k] (bf16, stride 3072): [q2 | h1 | q1 | x] blocks of 1024/1024/512/512
//   w1p[m][1024] = [w1 even cols | w1 odd cols]
//   w2p[o][3072] = [w2 even | w2 odd | wsk even | wsk odd]
// gemm1: A=A2[:,2048:] (K=1024) x w1p -> h1=bn1(relu(.+b1)) into A2[:,1024:2048]
// gemm2: A=A2 (K=3072) x w2p -> out=bn2(relu(.+b2+bsk))  (skip folded into K)

#define BS   16384
#define DIN  512
#define MID  1024
#define NOUT 512
#define KA2  3072
#define BN_EPS 1e-5f

typedef __attribute__((ext_vector_type(8))) short bf16x8;
typedef __attribute__((ext_vector_type(4))) float floatx4;

#define GLDS(g, l) __builtin_amdgcn_global_load_lds( \
    (const __attribute__((address_space(1))) void*)(g), \
    (__attribute__((address_space(3))) void*)(l), 16, 0, 0)

__device__ __forceinline__ void cvt_store8(const float* __restrict__ src,
                                           __hip_bfloat16* __restrict__ dst) {
    float4 u = *(const float4*)src;
    float4 v = *(const float4*)(src + 4);
    __hip_bfloat16 tmp[8] __attribute__((aligned(16)));
    tmp[0] = __float2bfloat16(u.x); tmp[1] = __float2bfloat16(u.y);
    tmp[2] = __float2bfloat16(u.z); tmp[3] = __float2bfloat16(u.w);
    tmp[4] = __float2bfloat16(v.x); tmp[5] = __float2bfloat16(v.y);
    tmp[6] = __float2bfloat16(v.z); tmp[7] = __float2bfloat16(v.w);
    *(float4*)dst = *(const float4*)tmp;
}

// strided (every-other) fp32 -> 8 packed bf16
__device__ __forceinline__ void cvt_store8_s2(const float* __restrict__ src,
                                              __hip_bfloat16* __restrict__ dst) {
    __hip_bfloat16 tmp[8] __attribute__((aligned(16)));
#pragma unroll
    for (int i = 0; i < 8; ++i) tmp[i] = __float2bfloat16(src[2 * i]);
    *(float4*)dst = *(const float4*)tmp;
}

#define T_Q2  ((long)BS * 128)          // 2,097,152 threads: q2 -> A2[:,0:1024]
#define T_Q1X ((long)BS * 64)           // 1,048,576: q1 -> A2[:,2048:2560], x -> [:,2560:3072]
#define T_W1  (1024L * 1024 / 8)        //   131,072: w1 -> w1p
#define T_W2  (512L * 3072 / 8)         //   196,608: w2/wsk -> w2p
#define T_ALL (T_Q2 + T_Q1X + T_W1 + T_W2)   // 3,473,408 = 13568 * 256

__global__ __launch_bounds__(256) void prep_all_kernel(
    const float* __restrict__ x, const float* __restrict__ q1,
    const float* __restrict__ q2, const float* __restrict__ w1,
    const float* __restrict__ w2, const float* __restrict__ wsk,
    __hip_bfloat16* __restrict__ A2,
    __hip_bfloat16* __restrict__ w1p, __hip_bfloat16* __restrict__ w2p)
{
    long id = (long)blockIdx.x * 256 + threadIdx.x;
    if (id < T_Q2) {
        long b = id >> 7;
        int j = (int)(id & 127) << 3;
        cvt_store8(q2 + b * MID + j, A2 + b * KA2 + j);
    } else if (id < T_Q2 + T_Q1X) {
        long id2 = id - T_Q2;
        long b = id2 >> 6;
        int j = (int)(id2 & 63) << 3;
        cvt_store8(q1 + b * DIN + j, A2 + b * KA2 + 2048 + j);
        cvt_store8(x  + b * DIN + j, A2 + b * KA2 + 2560 + j);
    } else if (id < T_Q2 + T_Q1X + T_W1) {
        long t = id - (T_Q2 + T_Q1X);
        long o8 = t * 8;                       // output index in w1p
        int m = (int)(o8 >> 10), k0 = (int)(o8 & 1023);
        const float* src = w1 + m * 1024 + ((k0 < 512) ? 2 * k0 : 2 * (k0 - 512) + 1);
        cvt_store8_s2(src, w1p + o8);
    } else {
        long t = id - (T_Q2 + T_Q1X + T_W1);
        long o8 = t * 8;                       // output index in w2p
        int o = (int)(o8 / 3072), k0 = (int)(o8 - (long)o * 3072);
        const float* src;
        if (k0 < 1024)      src = w2 + o * 2048 + 2 * k0;
        else if (k0 < 2048) src = w2 + o * 2048 + 2 * (k0 - 1024) + 1;
        else if (k0 < 2560) src = wsk + o * 1024 + 2 * (k0 - 2048);
        else                src = wsk + o * 1024 + 2 * (k0 - 2560) + 1;
        cvt_store8_s2(src, w2p + o8);
    }
}

// m97-style 128x128 bf16 MFMA GEMM, BK=32, 256 threads = 2x2 waves of 64x64.
// 1-D grid with XCD-aware swizzle: same-A-strip blocks pinned to one XCD.
// EPI==1: bn1(relu(+bias_a)) -> bf16 hout;  EPI==2: bn2(relu(+a+b)) -> fp32 fout
template <int EPI>
__global__ __launch_bounds__(256) void mfma_gemm(
    const __hip_bfloat16* __restrict__ A, const __hip_bfloat16* __restrict__ B,
    int K, long strideA,
    const float* __restrict__ bias_a, const float* __restrict__ bias_b,
    const float* __restrict__ bn_s, const float* __restrict__ bn_b,
    const float* __restrict__ bn_m, const float* __restrict__ bn_v,
    __hip_bfloat16* __restrict__ hout, float* __restrict__ fout, int strideOut)
{
    __shared__ short As[128 * 32];
    __shared__ short Bs[128 * 32];

    const int t = threadIdx.x;
    const int lane = t & 63;
    const int wave = t >> 6;
    const int wm = wave >> 1, wn = wave & 1;

    // swizzle: xcd = p&7; j = p>>3; mblk = xcd + 8*(j&15)  (0..127),
    // nblk = j>>4. All N-blocks of an M-strip share (p&7) -> same XCD.
    const int p = blockIdx.x;
    const int m0 = ((p & 7) + 8 * ((p >> 3) & 15)) * 128;
    const int n0 = ((p >> 3) >> 4) * 128;

    floatx4 acc[4][4];
#pragma unroll
    for (int i = 0; i < 4; ++i)
#pragma unroll
        for (int j = 0; j < 4; ++j)
            acc[i][j] = (floatx4){0.f, 0.f, 0.f, 0.f};

    for (int k0 = 0; k0 < K; k0 += 32) {
        // stage A,B tiles (128x32 bf16) via direct-to-LDS 16B loads.
        // LDS dest is wave-uniform base + lane*16 — layout must match.
#pragma unroll
        for (int c = 0; c < 2; ++c) {
            int fb = c * 256 + wave * 64;   // wave-uniform
            int f = fb + lane;              // row=f>>2, 16B chunk=f&3
            GLDS(A + (size_t)(m0 + (f >> 2)) * strideA + k0 + (f & 3) * 8,
                 As + fb * 8);
            GLDS(B + (size_t)(n0 + (f >> 2)) * (size_t)K + k0 + (f & 3) * 8,
                 Bs + fb * 8);
        }
        __syncthreads();

        bf16x8 af[4], bfr[4];
#pragma unroll
        for (int i = 0; i < 4; ++i)
            af[i] = *(const bf16x8*)&As[(wm * 64 + i * 16 + (lane & 15)) * 32 +
                                        (lane >> 4) * 8];
#pragma unroll
        for (int j = 0; j < 4; ++j)
            bfr[j] = *(const bf16x8*)&Bs[(wn * 64 + j * 16 + (lane & 15)) * 32 +
                                         (lane >> 4) * 8];
#pragma unroll
        for (int i = 0; i < 4; ++i)
#pragma unroll
            for (int j = 0; j < 4; ++j)
                acc[i][j] = __builtin_amdgcn_mfma_f32_16x16x32_bf16(
                    af[i], bfr[j], acc[i][j], 0, 0, 0);
        __syncthreads();
    }

    // epilogue: D frag mapping col=lane&15, row=(lane>>4)*4+r
#pragma unroll
    for (int j = 0; j < 4; ++j) {
        int col = n0 + wn * 64 + j * 16 + (lane & 15);
        float bias = bias_a[col];
        if (EPI == 2) bias += bias_b[col];
        float scale = bn_s[col] * rsqrtf(bn_v[col] + BN_EPS);
        float mean = bn_m[col], beta = bn_b[col];
#pragma unroll
        for (int i = 0; i < 4; ++i) {
            int rbase = m0 + wm * 64 + i * 16 + (lane >> 4) * 4;
#pragma unroll
            for (int r = 0; r < 4; ++r) {
                float v = acc[i][j][r] + bias;
                v = fmaxf(v, 0.f);
                v = (v - mean) * scale + beta;
                if (EPI == 1)
                    hout[(size_t)(rbase + r) * strideOut + col] = __float2bfloat16(v);
                else
                    fout[(size_t)(rbase + r) * strideOut + col] = v;
            }
        }
    }
}

extern "C" void kernel_launch(void* const* d_in, const int* in_sizes, int n_in,
                              void* d_out, int out_size, void* d_ws, size_t ws_size,
                              hipStream_t stream) {
    const float* x   = (const float*)d_in[0];
    const float* q1  = (const float*)d_in[1];
    const float* q2  = (const float*)d_in[2];
    const float* w1  = (const float*)d_in[3];
    const float* b1  = (const float*)d_in[4];
    const float* w2  = (const float*)d_in[5];
    const float* b2  = (const float*)d_in[6];
    const float* wsk = (const float*)d_in[7];
    const float* bsk = (const float*)d_in[8];
    const float* s1  = (const float*)d_in[9];
    const float* bb1 = (const float*)d_in[10];
    const float* m1  = (const float*)d_in[11];
    const float* v1  = (const float*)d_in[12];
    const float* s2  = (const float*)d_in[13];
    const float* bb2 = (const float*)d_in[14];
    const float* m2  = (const float*)d_in[15];
    const float* v2  = (const float*)d_in[16];
    float* out = (float*)d_out;

    // scratch: A2 (96MB) + w1p (2MB) + w2p (3MB). Prefer d_ws; else the
    // unused conv2_queue slots 1..3 (192MB, never read by the reference).
    size_t needA2 = (size_t)BS * KA2 * sizeof(__hip_bfloat16);
    size_t needW  = ((size_t)1024 * 1024 + (size_t)512 * 3072) * sizeof(__hip_bfloat16);
    char* base;
    if (ws_size >= needA2 + needW)
        base = (char*)d_ws;
    else
        base = (char*)d_in[2] + (size_t)BS * MID * sizeof(float);
    __hip_bfloat16* A2  = (__hip_bfloat16*)base;
    __hip_bfloat16* w1p = (__hip_bfloat16*)(base + needA2);
    __hip_bfloat16* w2p = w1p + 1024 * 1024;

    prep_all_kernel<<<dim3((int)(T_ALL / 256)), dim3(256), 0, stream>>>(
        x, q1, q2, w1, w2, wsk, A2, w1p, w2p);

    // gemm1: M=16384, N=1024, K=1024; h1 -> A2[:,1024:2048]
    mfma_gemm<1><<<dim3(1024), dim3(256), 0, stream>>>(
        A2 + 2048, w1p, 1024, KA2,
        b1, nullptr, s1, bb1, m1, v1,
        A2 + 1024, nullptr, KA2);

    // gemm2: M=16384, N=512, K=3072 (w2 + skip folded); out fp32
    mfma_gemm<2><<<dim3(512), dim3(256), 0, stream>>>(
        A2, w2p, 3072, KA2,
        b2, bsk, s2, bb2, m2, v2,
        nullptr, out, NOUT);
}